// Round 12
// baseline (239.663 us; speedup 1.0000x reference)
//
#include <hip/hip_runtime.h>
#include <hip/hip_bf16.h>

typedef unsigned long long ull;
typedef __attribute__((ext_vector_type(8))) short short8;
typedef __attribute__((ext_vector_type(8))) unsigned short us8;
typedef __attribute__((ext_vector_type(4))) unsigned short us4;
typedef __attribute__((ext_vector_type(4))) float f32x4;

constexpr int NN = 4096;   // nodes
constexpr int HH = 4;      // heads
constexpr int DD = 128;    // per-head dim
constexpr int NW = 64;     // 64-j tiles (= 64-bit mask words) per row
constexpr int JSPLIT = 8;  // j-range split (grid 1024 -> 4 blocks/CU)
constexpr float L2E = 1.44269504088896f;

// float -> bf16 RTNE (manual; used in cold paths)
__device__ inline unsigned short f2bf(float x) {
  unsigned u = __float_as_uint(x);
  u += 0x7FFFu + ((u >> 16) & 1u);
  return (unsigned short)(u >> 16);
}

// float -> bf16 via native cast (compiler emits v_cvt_pk_bf16_f32 for pairs)
__device__ inline short fbf(float x) {
  __bf16 b = (__bf16)x;
  short r;
  __builtin_memcpy(&r, &b, 2);
  return r;
}

// async 16B global->LDS (DMA; LDS dest = wave-uniform base + lane*16)
__device__ inline void gload16(const void* g, void* l) {
  __builtin_amdgcn_global_load_lds(
      (const __attribute__((address_space(1))) unsigned int*)g,
      (__attribute__((address_space(3))) unsigned int*)l, 16, 0, 0);
}

// ---------------------------------------------------------------------------
// adj (int32) -> transposed bitmask mbT[w][i] (bits j = w*64..w*64+63 of row i)
// ---------------------------------------------------------------------------
__global__ __launch_bounds__(256) void pack_mask_kernel(const int* __restrict__ adj,
                                                        ull* __restrict__ mbT) {
  const int i    = blockIdx.x;
  const int lane = threadIdx.x & 63;
  const int wave = threadIdx.x >> 6;
  for (int w = wave; w < NW; w += 4) {
    int v = adj[(size_t)i * NN + w * 64 + lane];
    ull m = __ballot(v > 0);
    if (lane == 0) mbT[(size_t)w * NN + i] = m;
  }
}

// ---------------------------------------------------------------------------
// fp32 -> bf16 elementwise (8/thread)
// ---------------------------------------------------------------------------
__global__ __launch_bounds__(256) void cvt_bf16_kernel(const float* __restrict__ in,
                                                       unsigned short* __restrict__ out,
                                                       int n8) {
  int i = blockIdx.x * 256 + threadIdx.x;
  if (i >= n8) return;
  f32x4 a = *(const f32x4*)(in + i * 8);
  f32x4 b = *(const f32x4*)(in + i * 8 + 4);
  us8 v;
#pragma unroll
  for (int q = 0; q < 4; ++q) { v[q] = f2bf(a[q]); v[q + 4] = f2bf(b[q]); }
  *(us8*)(out + i * 8) = v;
}

// ---------------------------------------------------------------------------
// W [H][K][128] fp32 -> WT bf16, tile-major swizzled: [h][kt][c][kc^(c&7)][8]
// ---------------------------------------------------------------------------
__global__ __launch_bounds__(256) void prep_w_kernel(const float* __restrict__ W,
                                                     unsigned short* __restrict__ WT,
                                                     int KT) {
  int id = blockIdx.x * 256 + threadIdx.x;
  int total = HH * KT * 128 * 8;
  if (id >= total) return;
  int kc = id & 7;
  int c  = (id >> 3) & 127;
  int kt = (id >> 10) % KT;
  int h  = id / (KT * 1024);
  int K  = KT * 64;
  const float* src = W + ((size_t)h * K + kt * 64 + kc * 8) * 128 + c;
  us8 v;
#pragma unroll
  for (int e = 0; e < 8; ++e) v[e] = f2bf(src[(size_t)e * 128]);
  *(us8*)(WT + (((size_t)(h * KT + kt) * 128 + c) * 64 + ((kc ^ (c & 7)) * 8))) = v;
}

// ---------------------------------------------------------------------------
// MFMA GEMM (validated): Wh = A(bf16) @ W(bf16).
// Outputs WhT (tiled-swizzled bf16) + per-row softmax factor tables:
//   eS = 2^(s*log2e), eS2 = 2^(0.2*s*log2e), eD/eD2 likewise for dst.
// (att's P-gen is then p = max(eS*eD, eS2*eD2): no trans op in the N^2 loop.)
// ---------------------------------------------------------------------------
__global__ __launch_bounds__(512) void gemm_mfma_kernel(
    const unsigned short* __restrict__ A, int sA, long hsA,
    const unsigned short* __restrict__ WT, int KT,
    unsigned short* __restrict__ WhT, const float* __restrict__ avec,
    float* __restrict__ eS, float* __restrict__ eS2,
    float* __restrict__ eD, float* __restrict__ eD2) {
  __shared__ unsigned short Al[2][64 * 64];
  __shared__ unsigned short Wl[2][128 * 64];
  __shared__ float sdred[2][64][2];
  const int t   = threadIdx.x;
  const int h   = blockIdx.y;
  const int i0  = blockIdx.x * 64;
  const int l   = t & 63;
  const int wv  = t >> 6;
  const int l15 = l & 15;
  const int l16 = l >> 4;
  const int wr  = (wv >> 1) * 16;
  const int wc  = (wv & 1) * 64;
  const unsigned short* Ab = A + (size_t)h * hsA;
  const unsigned short* Wb = WT + (size_t)h * KT * 8192;

  const int arowA = wv * 8 + (l >> 3);
  const int agA   = l & 7;

  f32x4 acc[4];
#pragma unroll
  for (int cf = 0; cf < 4; ++cf) acc[cf] = (f32x4){0.f, 0.f, 0.f, 0.f};

#define G_STAGE(kt_, b_)                                                          \
  {                                                                               \
    gload16(Ab + (size_t)(i0 + arowA) * sA + (kt_) * 64 + ((agA ^ (arowA & 7)) * 8), \
            &Al[b_][(wv * 64) * 8]);                                              \
    const unsigned short* wt = Wb + (size_t)(kt_)*8192;                           \
    gload16(wt + (size_t)(wv * 64 + l) * 8, &Wl[b_][(wv * 64) * 8]);              \
    gload16(wt + (size_t)(512 + wv * 64 + l) * 8, &Wl[b_][(512 + wv * 64) * 8]);  \
  }

  G_STAGE(0, 0);
  __syncthreads();
  int buf = 0;
  for (int kt = 0; kt < KT; ++kt) {
    if (kt + 1 < KT) G_STAGE(kt + 1, buf ^ 1);
    const int arow = wr + l15;
#pragma unroll
    for (int s = 0; s < 2; ++s) {
      int kc = s * 4 + l16;
      short8 a = *(const short8*)&Al[buf][arow * 64 + ((kc ^ (arow & 7)) * 8)];
#pragma unroll
      for (int cf = 0; cf < 4; ++cf) {
        int c = wc + cf * 16 + l15;
        short8 b = *(const short8*)&Wl[buf][c * 64 + ((kc ^ (c & 7)) * 8)];
        acc[cf] = __builtin_amdgcn_mfma_f32_16x16x32_bf16(a, b, acc[cf], 0, 0, 0);
      }
    }
    __syncthreads();
    buf ^= 1;
  }

  const int wblk = i0 >> 6;
  const int g    = (wr >> 3) + (l16 >> 1);
  const int eoff = (l16 * 4) & 7;
#pragma unroll
  for (int cf = 0; cf < 4; ++cf) {
    int c = wc + cf * 16 + l15;
    us4 pk;
#pragma unroll
    for (int r = 0; r < 4; ++r) pk[r] = f2bf(acc[cf][r]);
    *(us4*)(WhT + (((size_t)(h * 64 + wblk) * 128 + c) * 64 + ((g ^ (c & 7)) * 8) + eoff)) = pk;
  }

  float ps[4] = {0.f, 0.f, 0.f, 0.f}, pd[4] = {0.f, 0.f, 0.f, 0.f};
#pragma unroll
  for (int cf = 0; cf < 4; ++cf) {
    int c = wc + cf * 16 + l15;
    float as = avec[h * 2 * DD + c];
    float ad = avec[h * 2 * DD + DD + c];
#pragma unroll
    for (int r = 0; r < 4; ++r) { ps[r] += acc[cf][r] * as; pd[r] += acc[cf][r] * ad; }
  }
#pragma unroll
  for (int off = 1; off < 16; off <<= 1) {
#pragma unroll
    for (int r = 0; r < 4; ++r) {
      ps[r] += __shfl_xor(ps[r], off, 64);
      pd[r] += __shfl_xor(pd[r], off, 64);
    }
  }
  if (l15 == 0) {
#pragma unroll
    for (int r = 0; r < 4; ++r) {
      sdred[wv & 1][wr + l16 * 4 + r][0] = ps[r];
      sdred[wv & 1][wr + l16 * 4 + r][1] = pd[r];
    }
  }
  __syncthreads();
  if (t < 128) {
    int row = t >> 1, sel = t & 1;
    float v = (sdred[0][row][sel] + sdred[1][row][sel]) * L2E;
    float e1 = __builtin_amdgcn_exp2f(v);
    float e2 = __builtin_amdgcn_exp2f(0.2f * v);
    int gg = (h << 12) + i0 + row;
    if (sel) { eD[gg] = e1; eD2[gg] = e2; }
    else     { eS[gg] = e1; eS2[gg] = e2; }
  }
#undef G_STAGE
}

// ---------------------------------------------------------------------------
// MFMA attention PARTIAL, UNNORMALIZED, exp-factorized.
//   p_ij = mask ? max(eS_i*eD_j, eS2_i*eD2_j) : 0      (== exp2(lrelu(t)))
// 128 rows/block, 4 waves x 32 rows: each staged B-frag feeds 2 MFMAs
// (halves ds_read_b128 per MFMA).  JSPLIT=8 -> 1024 blocks, 4/CU.
// ---------------------------------------------------------------------------
__global__ __launch_bounds__(256, 4) void att_part_kernel(
    const unsigned short* __restrict__ WhT, const float* __restrict__ eS,
    const float* __restrict__ eS2, const float* __restrict__ eD,
    const float* __restrict__ eD2, const ull* __restrict__ mbT,
    float* __restrict__ part, float* __restrict__ sums) {
  __shared__ unsigned short whl[2][128 * 64];  // 32KB dbuf
  const int t   = threadIdx.x;
  const int h   = blockIdx.y;
  const int jq  = blockIdx.x & (JSPLIT - 1);
  const int i0  = (blockIdx.x / JSPLIT) * 128;
  const int l   = t & 63;
  const int wv  = t >> 6;
  const int l15 = l & 15;
  const int l16 = l >> 4;
  const int wr  = wv * 32;
  const int NIT = NW / JSPLIT;  // 8 j-tiles per block

  const int r0  = i0 + wr + l15;          // row-group 0 P-row
  const int g0  = (h << 12) + r0;
  const float es0 = eS[g0],      es0b = eS2[g0];
  const float es1 = eS[g0 + 16], es1b = eS2[g0 + 16];
  const float* pD  = eD  + (h << 12);
  const float* pD2 = eD2 + (h << 12);
  const unsigned short* Wt = WhT + (size_t)(h * 64) * 8192;
  const int w0 = jq * NIT;

  f32x4 acc0[8], acc1[8];
#pragma unroll
  for (int cf = 0; cf < 8; ++cf) {
    acc0[cf] = (f32x4){0.f, 0.f, 0.f, 0.f};
    acc1[cf] = (f32x4){0.f, 0.f, 0.f, 0.f};
  }
  float ps0 = 0.f, ps1 = 0.f;

#define A_STAGE(w_, b_)                                                    \
  {                                                                        \
    const unsigned short* gt = Wt + (size_t)(w_)*8192;                     \
    gload16(gt + (size_t)(0 * 256 + t) * 8, &whl[b_][(0 * 256 + wv * 64) * 8]); \
    gload16(gt + (size_t)(1 * 256 + t) * 8, &whl[b_][(1 * 256 + wv * 64) * 8]); \
    gload16(gt + (size_t)(2 * 256 + t) * 8, &whl[b_][(2 * 256 + wv * 64) * 8]); \
    gload16(gt + (size_t)(3 * 256 + t) * 8, &whl[b_][(3 * 256 + wv * 64) * 8]); \
  }

  A_STAGE(w0, 0);
  __syncthreads();
  int buf = 0;
  for (int it = 0; it < NIT; ++it) {
    const int w = w0 + it;
    if (it + 1 < NIT) A_STAGE(w + 1, buf ^ 1);
    // P-gen into A-frags for both 16-row groups (lane: row=l15, kchunk=l16)
    ull mb0 = mbT[(size_t)w * NN + r0];
    ull mb1 = mbT[(size_t)w * NN + r0 + 16];
    short8 a0[2], a1[2];
#pragma unroll
    for (int s = 0; s < 2; ++s) {
      const int bsh = s * 32 + l16 * 8;
      f32x4 dA  = *(const f32x4*)(pD  + w * 64 + bsh);
      f32x4 dB  = *(const f32x4*)(pD  + w * 64 + bsh + 4);
      f32x4 d2A = *(const f32x4*)(pD2 + w * 64 + bsh);
      f32x4 d2B = *(const f32x4*)(pD2 + w * 64 + bsh + 4);
      unsigned m0 = (unsigned)((mb0 >> bsh) & 0xffull);
      unsigned m1 = (unsigned)((mb1 >> bsh) & 0xffull);
#pragma unroll
      for (int q = 0; q < 8; ++q) {
        float ed  = (q < 4) ? dA[q] : dB[q - 4];
        float ed2 = (q < 4) ? d2A[q] : d2B[q - 4];
        float p0 = fmaxf(es0 * ed, es0b * ed2);
        p0 = ((m0 >> q) & 1u) ? p0 : 0.f;
        ps0 += p0;
        a0[s][q] = fbf(p0);
        float p1 = fmaxf(es1 * ed, es1b * ed2);
        p1 = ((m1 >> q) & 1u) ? p1 : 0.f;
        ps1 += p1;
        a1[s][q] = fbf(p1);
      }
    }
    __builtin_amdgcn_s_setprio(1);
#pragma unroll
    for (int s = 0; s < 2; ++s) {
      int kc = s * 4 + l16;
#pragma unroll
      for (int cf = 0; cf < 8; ++cf) {
        int c = cf * 16 + l15;
        short8 b = *(const short8*)&whl[buf][c * 64 + ((kc ^ (c & 7)) * 8)];
        acc0[cf] = __builtin_amdgcn_mfma_f32_16x16x32_bf16(a0[s], b, acc0[cf], 0, 0, 0);
        acc1[cf] = __builtin_amdgcn_mfma_f32_16x16x32_bf16(a1[s], b, acc1[cf], 0, 0, 0);
      }
    }
    __builtin_amdgcn_s_setprio(0);
    __syncthreads();
    buf ^= 1;
  }
  // row-sum reduce: lanes {l15, l15+16, l15+32, l15+48} hold same row
  ps0 += __shfl_xor(ps0, 16, 64);
  ps0 += __shfl_xor(ps0, 32, 64);
  ps1 += __shfl_xor(ps1, 16, 64);
  ps1 += __shfl_xor(ps1, 32, 64);
  if (l16 == 0) {
    sums[(size_t)jq * (HH * NN) + g0] = ps0;
    sums[(size_t)jq * (HH * NN) + g0 + 16] = ps1;
  }
  // partial store (fp32): D col = l&15, row = (l>>4)*4 + reg
  float* pb = part + ((size_t)jq * (HH * NN) + (h << 12) + i0) * 128;
#pragma unroll
  for (int cf = 0; cf < 8; ++cf) {
#pragma unroll
    for (int r = 0; r < 4; ++r) {
      pb[(size_t)(wr + l16 * 4 + r) * 128 + cf * 16 + l15] = acc0[cf][r];
      pb[(size_t)(wr + 16 + l16 * 4 + r) * 128 + cf * 16 + l15] = acc1[cf][r];
    }
  }
#undef A_STAGE
}

// ---------------------------------------------------------------------------
// Fuse: out[node, h*128+c] = elu( (sum_q part_q) / (sum_q sums_q) ).
// OUTBF: bf16 (stage-1 x).
// ---------------------------------------------------------------------------
template <int OUTBF>
__global__ __launch_bounds__(256) void fuse_kernel(const float* __restrict__ part,
                                                   const float* __restrict__ sums,
                                                   void* __restrict__ outp) {
  int idx = blockIdx.x * 256 + threadIdx.x;   // one f32x4 per thread
  int c4 = (idx & 31) * 4;
  int g = idx >> 5;
  int node = g & (NN - 1), h = g >> 12;
  f32x4 a = (f32x4){0.f, 0.f, 0.f, 0.f};
  float den = 0.f;
#pragma unroll
  for (int q = 0; q < JSPLIT; ++q) {
    f32x4 v = *(const f32x4*)(part + ((size_t)q * (HH * NN) + g) * 128 + c4);
#pragma unroll
    for (int r = 0; r < 4; ++r) a[r] += v[r];
    den += sums[(size_t)q * (HH * NN) + g];
  }
  float inv = 1.0f / den;
  size_t o = (size_t)node * (HH * DD) + h * DD + c4;
#pragma unroll
  for (int r = 0; r < 4; ++r) {
    float v = a[r] * inv;
    a[r] = v > 0.f ? v : __expf(v) - 1.f;
  }
  if (OUTBF) {
    us4 pk;
#pragma unroll
    for (int r = 0; r < 4; ++r) pk[r] = (unsigned short)fbf(a[r]);
    *(us4*)((unsigned short*)outp + o) = pk;
  } else {
    *(f32x4*)((float*)outp + o) = a;
  }
}

// ---------------------------------------------------------------------------
extern "C" void kernel_launch(void* const* d_in, const int* in_sizes, int n_in,
                              void* d_out, int out_size, void* d_ws, size_t ws_size,
                              hipStream_t stream) {
  const float* chems = (const float*)d_in[0];  // [H, N, 128]
  const int*   adj   = (const int*)d_in[1];    // [N, N]
  const float* W1    = (const float*)d_in[2];  // [H, 128, 128]
  const float* a1    = (const float*)d_in[3];  // [H, 256]
  const float* W2    = (const float*)d_in[4];  // [H, 512, 128]
  const float* a2    = (const float*)d_in[5];  // [H, 256]
  float* out = (float*)d_out;                  // [N, 512] fp32

  char* p = (char*)d_ws;
  auto alloc = [&](size_t bytes) { char* r = p; p += (bytes + 255) & ~255ull; return r; };
  ull*   mbT  = (ull*)alloc((size_t)NW * NN * 8);                        // 2 MB
  unsigned short* cbf  = (unsigned short*)alloc((size_t)HH * NN * DD * 2);   // 4 MB
  unsigned short* xbf  = (unsigned short*)alloc((size_t)NN * HH * DD * 2);   // 4 MB
  unsigned short* WhT1 = (unsigned short*)alloc((size_t)HH * 64 * 8192 * 2); // 4 MB
  unsigned short* WhT2 = (unsigned short*)alloc((size_t)HH * 64 * 8192 * 2); // 4 MB
  unsigned short* WT1  = (unsigned short*)alloc((size_t)HH * 2 * 8192 * 2);  // 128 KB
  unsigned short* WT2  = (unsigned short*)alloc((size_t)HH * 8 * 8192 * 2);  // 512 KB
  float* parts = (float*)alloc((size_t)JSPLIT * HH * NN * 128 * 4);      // 64 MB (reused)
  float* sums  = (float*)alloc((size_t)JSPLIT * HH * NN * 4);            // 512 KB
  float* eS1  = (float*)alloc((size_t)HH * NN * 4);
  float* eS1b = (float*)alloc((size_t)HH * NN * 4);
  float* eD1  = (float*)alloc((size_t)HH * NN * 4);
  float* eD1b = (float*)alloc((size_t)HH * NN * 4);
  float* eS2  = (float*)alloc((size_t)HH * NN * 4);
  float* eS2b = (float*)alloc((size_t)HH * NN * 4);
  float* eD2  = (float*)alloc((size_t)HH * NN * 4);
  float* eD2b = (float*)alloc((size_t)HH * NN * 4);
  (void)ws_size; (void)in_sizes; (void)n_in; (void)out_size;

  pack_mask_kernel<<<NN, 256, 0, stream>>>(adj, mbT);
  cvt_bf16_kernel<<<(HH * NN * DD / 8 + 255) / 256, 256, 0, stream>>>(chems, cbf,
                                                                      HH * NN * DD / 8);
  prep_w_kernel<<<(HH * 2 * 1024 + 255) / 256, 256, 0, stream>>>(W1, WT1, 2);
  prep_w_kernel<<<(HH * 8 * 1024 + 255) / 256, 256, 0, stream>>>(W2, WT2, 8);

  const int FUSE_BLK = (HH * NN * DD / 4) / 256;  // 2048

  // ---- stage 1 ----
  gemm_mfma_kernel<<<dim3(NN / 64, HH), 512, 0, stream>>>(
      cbf, DD, (long)NN * DD, WT1, 2, WhT1, a1, eS1, eS1b, eD1, eD1b);
  att_part_kernel<<<dim3(JSPLIT * NN / 128, HH), 256, 0, stream>>>(
      WhT1, eS1, eS1b, eD1, eD1b, mbT, parts, sums);
  fuse_kernel<1><<<FUSE_BLK, 256, 0, stream>>>(parts, sums, xbf);
  // ---- stage 2 ----
  gemm_mfma_kernel<<<dim3(NN / 64, HH), 512, 0, stream>>>(
      xbf, HH * DD, 0L, WT2, 8, WhT2, a2, eS2, eS2b, eD2, eD2b);
  att_part_kernel<<<dim3(JSPLIT * NN / 128, HH), 256, 0, stream>>>(
      WhT2, eS2, eS2b, eD2, eD2b, mbT, parts, sums);
  fuse_kernel<0><<<FUSE_BLK, 256, 0, stream>>>(parts, sums, out);
}